// Round 5
// baseline (596.302 us; speedup 1.0000x reference)
//
#include <hip/hip_runtime.h>

typedef _Float16 half_t;
typedef __attribute__((ext_vector_type(8))) _Float16 half8;
typedef __attribute__((ext_vector_type(4))) _Float16 half4;
typedef __attribute__((ext_vector_type(4))) float float4_t;
typedef float f4u __attribute__((ext_vector_type(4), aligned(4)));  // 4B-aligned float4

#define BN_EPS 1e-5f

constexpr int Nn = 64, Cc = 64, Tt = 300, Vv = 25, Ss = 3;
constexpr int XA_S = 72;   // c-stride of wave-private xa rows (144 B: 16B-aligned, ~2-way banks)
constexpr int KCH  = 5;    // chunks per block; 4 timesteps/chunk -> 20 t per block; 300 = 15*20

// ---------------- precompute: fragment-major fp16 tables into workspace ----------------
// aeh[s][wt][lane][8] : Ae^T fragment  B[k=v][n=w], v=(lane>>4)*8+j, w=wt*16+(lane&15), zero-padded
// wch[s][ot][ks][lane][8] : Wc fragment A[m=o][k=c], o=ot*16+(lane&15), c=ks*32+(lane>>4)*8+j
// bnsc/bnsh[64] : BN scale/shift with sum_s bc folded in
__global__ __launch_bounds__(256, 1)
void gcn_pre(const float* __restrict__ A,   const float* __restrict__ PA1,
             const float* __restrict__ PA2, const float* __restrict__ Wc,
             const float* __restrict__ bc,  const float* __restrict__ gamma,
             const float* __restrict__ beta, const float* __restrict__ rmean,
             const float* __restrict__ rvar,
             half_t* __restrict__ aeh, half_t* __restrict__ wch,
             float* __restrict__ bnsc, float* __restrict__ bnsh)
{
    const int tid = threadIdx.x;
    if (tid < Cc) {
        float sc   = gamma[tid] * rsqrtf(rvar[tid] + BN_EPS);
        float bsum = bc[tid] + bc[Cc + tid] + bc[2 * Cc + tid];
        bnsc[tid] = sc;
        bnsh[tid] = beta[tid] - rmean[tid] * sc + bsum * sc;
    }
    for (int e = tid; e < Ss * 2 * 64; e += 256) {        // AeT fragments
        int s = e >> 7, wt = (e >> 6) & 1, lane = e & 63;
        int col = lane & 15, q = lane >> 4;
        int w = wt * 16 + col;
        #pragma unroll
        for (int j = 0; j < 8; ++j) {
            int v = q * 8 + j;
            float val = 0.f;
            if (v < Vv && w < Vv) {
                int ai = (s * Vv + v) * Vv + w;
                val = A[ai] * PA1[ai] + PA2[ai];
            }
            aeh[e * 8 + j] = (half_t)val;
        }
    }
    for (int e = tid; e < Ss * 4 * 2 * 64; e += 256) {    // Wc fragments
        int s = e >> 9, r = e & 511, ot = r >> 7, ks = (r >> 6) & 1, lane = r & 63;
        int col = lane & 15, q = lane >> 4;
        int o = ot * 16 + col;
        #pragma unroll
        for (int j = 0; j < 8; ++j) {
            int c = ks * 32 + q * 8 + j;
            wch[e * 8 + j] = (half_t)Wc[(s * Cc + o) * Cc + c];
        }
    }
}

// -------- main: barrier-free, wave-owns-timestep, 5-chunk pipeline per block --------
__global__ __launch_bounds__(256, 4)
void gcn_main(const float* __restrict__ x, const half_t* __restrict__ aeh,
              const half_t* __restrict__ wch, const float* __restrict__ bnsc,
              const float* __restrict__ bnsh, float* __restrict__ out)
{
    // wave-private xa transpose scratch: [wave][w 0..31][c 0..63 +pad] = 18432 B
    __shared__ __align__(16) half_t xaW[4][32][XA_S];

    const int tid  = threadIdx.x;
    const int lane = tid & 63;
    const int wave = tid >> 6;      // 0..3
    const int col  = lane & 15;
    const int quad = lane >> 4;

    const int n     = blockIdx.y;
    const int tbase = blockIdx.x * (4 * KCH);   // 20-timestep span, exact

    // 32-bit row offsets for this lane's af rows: c = ct*16+col
    // off(ct, tg) = (n*Cc + ct*16+col)*7500 + tg*25   (max ~30.7M, fits 32-bit)
    const int rbase = (n * Cc + col) * (Tt * Vv);

    f4u   pa_[4][2];   // raw f32 prefetch (quad<3 lanes)
    float p24_[4];     // v=24 tail (quad==3 lanes)
    half8 afc[4], afn[4];

    auto issue_pf = [&](int tg) {
        if (quad < 3) {
            #pragma unroll
            for (int ct = 0; ct < 4; ++ct) {
                const float* p = x + (size_t)(rbase + ct * 16 * (Tt * Vv) + tg * Vv + quad * 8);
                pa_[ct][0] = *(const f4u*)p;
                pa_[ct][1] = *(const f4u*)(p + 4);
            }
        } else {
            #pragma unroll
            for (int ct = 0; ct < 4; ++ct)
                p24_[ct] = x[(size_t)(rbase + ct * 16 * (Tt * Vv) + tg * Vv + 24)];
        }
    };
    auto cvt_pf = [&]() {
        #pragma unroll
        for (int ct = 0; ct < 4; ++ct) {
            half8 h;
            if (quad < 3) {
                #pragma unroll
                for (int j = 0; j < 4; ++j) {
                    h[j]     = (half_t)pa_[ct][0][j];
                    h[4 + j] = (half_t)pa_[ct][1][j];
                }
            } else {
                h[0] = (half_t)p24_[ct];           // v=24; v=25..31 are K-pad zeros
                #pragma unroll
                for (int j = 1; j < 8; ++j) h[j] = (half_t)0.f;
            }
            afn[ct] = h;
        }
    };

    const float4_t zero4 = {0.f, 0.f, 0.f, 0.f};

    // prologue: chunk-0 fragments (cold latency paid once per block)
    issue_pf(tbase + wave);
    cvt_pf();
    #pragma unroll
    for (int ct = 0; ct < 4; ++ct) afc[ct] = afn[ct];

    for (int k = 0; k < KCH; ++k) {
        const int tg = tbase + k * 4 + wave;

        // issue next chunk's x loads now; converted after s==1 (~2 stages of cover)
        if (k + 1 < KCH) issue_pf(tbase + (k + 1) * 4 + wave);

        float4_t yacc[4][2];
        #pragma unroll
        for (int ot = 0; ot < 4; ++ot)
            #pragma unroll
            for (int wt = 0; wt < 2; ++wt) yacc[ot][wt] = zero4;

        #pragma unroll
        for (int s = 0; s < Ss; ++s) {
            // ---- stage 1: xa[c][w] = x · Ae[s] (8 MFMA); ab reloaded per wt (L1-hot) ----
            #pragma unroll
            for (int wt = 0; wt < 2; ++wt) {
                half8 abw = *(const half8*)&aeh[((s * 2 + wt) * 64 + lane) * 8];
                #pragma unroll
                for (int ct = 0; ct < 4; ++ct) {
                    float4_t r = __builtin_amdgcn_mfma_f32_16x16x32_f16(afc[ct], abw, zero4, 0, 0, 0);
                    half4 h;
                    #pragma unroll
                    for (int i = 0; i < 4; ++i) h[i] = (half_t)r[i];
                    *(half4*)&xaW[wave][wt * 16 + col][ct * 16 + quad * 4] = h;
                }
            }
            if (s == 1 && k + 1 < KCH) cvt_pf();   // loads have had ~1.5 stages to land

            // ---- stage 2: y += Wc[s] · xa  (16 MFMA); 2 bf frags live at a time ----
            #pragma unroll
            for (int ks = 0; ks < 2; ++ks) {
                half8 bf0 = *(const half8*)&xaW[wave][     col][ks * 32 + quad * 8];
                half8 bf1 = *(const half8*)&xaW[wave][16 + col][ks * 32 + quad * 8];
                #pragma unroll
                for (int ot = 0; ot < 4; ++ot) {
                    half8 wk = *(const half8*)&wch[(((s * 4 + ot) * 2 + ks) * 64 + lane) * 8];
                    yacc[ot][0] = __builtin_amdgcn_mfma_f32_16x16x32_f16(wk, bf0, yacc[ot][0], 0, 0, 0);
                    yacc[ot][1] = __builtin_amdgcn_mfma_f32_16x16x32_f16(wk, bf1, yacc[ot][1], 0, 0, 0);
                }
            }
        }

        // ---- epilogue: BN + residual (x re-read, L1/L2-hot from af loads) + ReLU ----
        const size_t base = (size_t)n * Cc * Tt * Vv + (size_t)tg * Vv;
        const float* xr   = x + base;
        float* outr       = out + base;
        #pragma unroll
        for (int ot = 0; ot < 4; ++ot) {
            float4_t sc = *(const float4_t*)&bnsc[ot * 16 + quad * 4];   // L1-hot
            float4_t sh = *(const float4_t*)&bnsh[ot * 16 + quad * 4];
            #pragma unroll
            for (int i = 0; i < 4; ++i) {
                const int ro = (ot * 16 + quad * 4 + i) * (Tt * Vv);
                #pragma unroll
                for (int wt = 0; wt < 2; ++wt) {
                    int w = wt * 16 + col;
                    if (w < Vv) {
                        float val = yacc[ot][wt][i] * sc[i] + sh[i] + xr[ro + w];
                        outr[ro + w] = fmaxf(val, 0.f);
                    }
                }
            }
        }

        if (k + 1 < KCH) {
            #pragma unroll
            for (int ct = 0; ct < 4; ++ct) afc[ct] = afn[ct];
        }
    }
}

extern "C" void kernel_launch(void* const* d_in, const int* in_sizes, int n_in,
                              void* d_out, int out_size, void* d_ws, size_t ws_size,
                              hipStream_t stream) {
    const float* x     = (const float*)d_in[0];
    const float* A     = (const float*)d_in[1];
    const float* PA1   = (const float*)d_in[2];
    const float* PA2   = (const float*)d_in[3];
    const float* Wc    = (const float*)d_in[4];
    const float* bc    = (const float*)d_in[5];
    const float* gamma = (const float*)d_in[6];
    const float* beta  = (const float*)d_in[7];
    const float* rmean = (const float*)d_in[8];
    const float* rvar  = (const float*)d_in[9];
    float* out = (float*)d_out;

    // workspace layout (37,376 B): aeh | wch | bnsc | bnsh
    half_t* aeh = (half_t*)d_ws;                      // 3*2*64*8  = 3072 halfs
    half_t* wch = aeh + Ss * 2 * 64 * 8;              // 3*4*2*64*8 = 12288 halfs
    float* bnsc = (float*)(wch + Ss * 4 * 2 * 64 * 8);
    float* bnsh = bnsc + Cc;

    gcn_pre<<<dim3(1), 256, 0, stream>>>(A, PA1, PA2, Wc, bc, gamma, beta, rmean, rvar,
                                         aeh, wch, bnsc, bnsh);
    // (15, 64) = 960 blocks -> single co-resident round at 4 blocks/CU
    gcn_main<<<dim3(Tt / (4 * KCH), Nn), 256, 0, stream>>>(x, aeh, wch, bnsc, bnsh, out);
}

// Round 6
// 364.173 us; speedup vs baseline: 1.6374x; 1.6374x over previous
//
#include <hip/hip_runtime.h>

typedef _Float16 half_t;
typedef __attribute__((ext_vector_type(8))) _Float16 half8;
typedef __attribute__((ext_vector_type(4))) _Float16 half4;
typedef __attribute__((ext_vector_type(4))) float float4_t;

#define BN_EPS 1e-5f

constexpr int Nn = 64, Cc = 64, Tt = 300, Vv = 25, Ss = 3;
constexpr int XA_S = 72;   // c-stride of wave-private xa rows (144 B: 16B-aligned, ~2-way banks)
constexpr int KCH  = 5;    // chunks per block; 4 timesteps/chunk -> 20 t per block; 300 = 15*20
constexpr int CHF  = Cc * 4 * Vv;   // 6400 floats per x-chunk (= 1600 float4, = 25 wave-instrs)

// ---------------- precompute: fragment-major fp16 tables into workspace ----------------
// aeh[s][wt][lane][8] : Ae^T fragment  B[k=v][n=w], v=(lane>>4)*8+j, w=wt*16+(lane&15), zero-padded
// wch[s][ot][ks][lane][8] : Wc fragment A[m=o][k=c], o=ot*16+(lane&15), c=ks*32+(lane>>4)*8+j
// bnsc/bnsh[64] : BN scale/shift with sum_s bc folded in
__global__ __launch_bounds__(256, 1)
void gcn_pre(const float* __restrict__ A,   const float* __restrict__ PA1,
             const float* __restrict__ PA2, const float* __restrict__ Wc,
             const float* __restrict__ bc,  const float* __restrict__ gamma,
             const float* __restrict__ beta, const float* __restrict__ rmean,
             const float* __restrict__ rvar,
             half_t* __restrict__ aeh, half_t* __restrict__ wch,
             float* __restrict__ bnsc, float* __restrict__ bnsh)
{
    const int tid = threadIdx.x;
    if (tid < Cc) {
        float sc   = gamma[tid] * rsqrtf(rvar[tid] + BN_EPS);
        float bsum = bc[tid] + bc[Cc + tid] + bc[2 * Cc + tid];
        bnsc[tid] = sc;
        bnsh[tid] = beta[tid] - rmean[tid] * sc + bsum * sc;
    }
    for (int e = tid; e < Ss * 2 * 64; e += 256) {        // AeT fragments
        int s = e >> 7, wt = (e >> 6) & 1, lane = e & 63;
        int col = lane & 15, q = lane >> 4;
        int w = wt * 16 + col;
        #pragma unroll
        for (int j = 0; j < 8; ++j) {
            int v = q * 8 + j;
            float val = 0.f;
            if (v < Vv && w < Vv) {
                int ai = (s * Vv + v) * Vv + w;
                val = A[ai] * PA1[ai] + PA2[ai];
            }
            aeh[e * 8 + j] = (half_t)val;
        }
    }
    for (int e = tid; e < Ss * 4 * 2 * 64; e += 256) {    // Wc fragments
        int s = e >> 9, r = e & 511, ot = r >> 7, ks = (r >> 6) & 1, lane = r & 63;
        int col = lane & 15, q = lane >> 4;
        int o = ot * 16 + col;
        #pragma unroll
        for (int j = 0; j < 8; ++j) {
            int c = ks * 32 + q * 8 + j;
            wch[e * 8 + j] = (half_t)Wc[(s * Cc + o) * Cc + c];
        }
    }
}

// ---- main: barrier-light, wave-owns-timestep, LDS double-buffered x via global_load_lds ----
__global__ __launch_bounds__(256, 2)
void gcn_main(const float* __restrict__ x, const half_t* __restrict__ aeh,
              const half_t* __restrict__ wch, const float* __restrict__ bnsc,
              const float* __restrict__ bnsh, float* __restrict__ out)
{
    // wave-private xa transpose scratch: [wave][w 0..31][c 0..63 +pad] = 18432 B
    __shared__ __align__(16) half_t xaW[4][32][XA_S];
    // x-chunk double buffer, raw fp32 global layout [c][t 0..3][v 0..24] = 2 x 25600 B
    __shared__ __align__(16) float xbuf[2][CHF];
    // total 69632 B -> 2 blocks/CU -> 256-reg unified budget per wave

    const int tid  = threadIdx.x;
    const int lane = tid & 63;
    const int wave = tid >> 6;      // 0..3 -> owns timestep (chunk*4 + wave)
    const int col  = lane & 15;
    const int quad = lane >> 4;

    const int n     = blockIdx.y;
    const int tbase = blockIdx.x * (4 * KCH);   // 20-timestep span, exact
    const float* xb = x + (size_t)n * Cc * Tt * Vv;

    // ---- chunk-0 async stage: 25 global_load_lds_dwordx4 (wave i%4 partition) ----
    {
        const int t0 = tbase;
        for (int i = wave; i < 25; i += 4) {
            int idx = i * 64 + lane;              // float4 index 0..1599
            int c = idx / 25, p = idx - c * 25;
            const float* g = xb + c * (Tt * Vv) + t0 * Vv + p * 4;   // 16B-aligned
            __builtin_amdgcn_global_load_lds(
                (const __attribute__((address_space(1))) unsigned int*)g,
                (__attribute__((address_space(3))) unsigned int*)&xbuf[0][i * 256],
                16, 0, 0);
        }
    }

    // ---- all tables into registers (overlaps chunk-0 DMA latency) ----
    half8 ab[Ss][2];
    #pragma unroll
    for (int s = 0; s < Ss; ++s)
        #pragma unroll
        for (int wt = 0; wt < 2; ++wt)
            ab[s][wt] = *(const half8*)&aeh[((s * 2 + wt) * 64 + lane) * 8];

    half8 wfr[Ss][2][4];                          // [s][ks][ot] : 24 x half8 = 96 regs
    #pragma unroll
    for (int s = 0; s < Ss; ++s)
        #pragma unroll
        for (int ks = 0; ks < 2; ++ks)
            #pragma unroll
            for (int ot = 0; ot < 4; ++ot)
                wfr[s][ks][ot] = *(const half8*)&wch[(((s * 4 + ot) * 2 + ks) * 64 + lane) * 8];

    float4_t scr[4], shr[4];
    #pragma unroll
    for (int ot = 0; ot < 4; ++ot) {
        scr[ot] = *(const float4_t*)&bnsc[ot * 16 + quad * 4];
        shr[ot] = *(const float4_t*)&bnsh[ot * 16 + quad * 4];
    }

    __syncthreads();   // chunk-0 DMA drained (vmcnt) + visible to all waves

    const float4_t zero4 = {0.f, 0.f, 0.f, 0.f};
    int cur = 0;

    for (int k = 0; k < KCH; ++k) {
        // ---- issue next chunk's DMA into the other buffer (completes during compute) ----
        if (k + 1 < KCH) {
            const int t0 = tbase + (k + 1) * 4;
            for (int i = wave; i < 25; i += 4) {
                int idx = i * 64 + lane;
                int c = idx / 25, p = idx - c * 25;
                const float* g = xb + c * (Tt * Vv) + t0 * Vv + p * 4;
                __builtin_amdgcn_global_load_lds(
                    (const __attribute__((address_space(1))) unsigned int*)g,
                    (__attribute__((address_space(3))) unsigned int*)&xbuf[cur ^ 1][i * 256],
                    16, 0, 0);
            }
        }

        // ---- af fragments from LDS x-chunk: af[ct] = x[c=ct*16+col][t=wave][v=quad*8+j] ----
        half8 afc[4];
        #pragma unroll
        for (int ct = 0; ct < 4; ++ct) {
            const float* r = &xbuf[cur][(ct * 16 + col) * 100 + wave * 25];
            half8 h;
            if (quad < 3) {
                #pragma unroll
                for (int j = 0; j < 8; ++j) h[j] = (half_t)r[quad * 8 + j];
            } else {
                h[0] = (half_t)r[24];             // v=24; v=25..31 are K-pad zeros
                #pragma unroll
                for (int j = 1; j < 8; ++j) h[j] = (half_t)0.f;
            }
            afc[ct] = h;
        }

        float4_t yacc[4][2];
        #pragma unroll
        for (int ot = 0; ot < 4; ++ot)
            #pragma unroll
            for (int wt = 0; wt < 2; ++wt) yacc[ot][wt] = zero4;

        #pragma unroll
        for (int s = 0; s < Ss; ++s) {
            // ---- stage 1: xa[c][w] = x · Ae[s] (8 MFMA) ----
            #pragma unroll
            for (int ct = 0; ct < 4; ++ct)
                #pragma unroll
                for (int wt = 0; wt < 2; ++wt) {
                    float4_t r = __builtin_amdgcn_mfma_f32_16x16x32_f16(afc[ct], ab[s][wt], zero4, 0, 0, 0);
                    half4 h;
                    #pragma unroll
                    for (int i = 0; i < 4; ++i) h[i] = (half_t)r[i];
                    *(half4*)&xaW[wave][wt * 16 + col][ct * 16 + quad * 4] = h;
                }
            // ---- same-wave transpose readback (lgkmcnt-ordered, no barrier) ----
            half8 bf[2][2];
            #pragma unroll
            for (int ks = 0; ks < 2; ++ks)
                #pragma unroll
                for (int wt = 0; wt < 2; ++wt)
                    bf[ks][wt] = *(const half8*)&xaW[wave][wt * 16 + col][ks * 32 + quad * 8];
            // ---- stage 2: y += Wc[s] · xa (16 MFMA), weights in registers ----
            #pragma unroll
            for (int ot = 0; ot < 4; ++ot)
                #pragma unroll
                for (int wt = 0; wt < 2; ++wt) {
                    yacc[ot][wt] = __builtin_amdgcn_mfma_f32_16x16x32_f16(wfr[s][0][ot], bf[0][wt], yacc[ot][wt], 0, 0, 0);
                    yacc[ot][wt] = __builtin_amdgcn_mfma_f32_16x16x32_f16(wfr[s][1][ot], bf[1][wt], yacc[ot][wt], 0, 0, 0);
                }
        }

        // ---- epilogue: BN + residual (x from LDS!) + ReLU, coalesced-ish stores ----
        const int tg = tbase + k * 4 + wave;
        float* outr = out + (size_t)n * Cc * Tt * Vv + (size_t)tg * Vv;
        #pragma unroll
        for (int ot = 0; ot < 4; ++ot) {
            #pragma unroll
            for (int i = 0; i < 4; ++i) {
                const int o  = ot * 16 + quad * 4 + i;
                const int ro = o * (Tt * Vv);
                #pragma unroll
                for (int wt = 0; wt < 2; ++wt) {
                    int w = wt * 16 + col;
                    if (w < Vv) {
                        float val = yacc[ot][wt][i] * scr[ot][i] + shr[ot][i]
                                  + xbuf[cur][o * 100 + wave * 25 + w];
                        outr[ro + w] = fmaxf(val, 0.f);
                    }
                }
            }
        }

        if (k + 1 < KCH) {
            __syncthreads();   // drains next-chunk DMA (vmcnt) + protects xbuf[cur] rewrite
            cur ^= 1;
        }
    }
}

extern "C" void kernel_launch(void* const* d_in, const int* in_sizes, int n_in,
                              void* d_out, int out_size, void* d_ws, size_t ws_size,
                              hipStream_t stream) {
    const float* x     = (const float*)d_in[0];
    const float* A     = (const float*)d_in[1];
    const float* PA1   = (const float*)d_in[2];
    const float* PA2   = (const float*)d_in[3];
    const float* Wc    = (const float*)d_in[4];
    const float* bc    = (const float*)d_in[5];
    const float* gamma = (const float*)d_in[6];
    const float* beta  = (const float*)d_in[7];
    const float* rmean = (const float*)d_in[8];
    const float* rvar  = (const float*)d_in[9];
    float* out = (float*)d_out;

    // workspace layout (37,376 B): aeh | wch | bnsc | bnsh
    half_t* aeh = (half_t*)d_ws;                      // 3*2*64*8  = 3072 halfs
    half_t* wch = aeh + Ss * 2 * 64 * 8;              // 3*4*2*64*8 = 12288 halfs
    float* bnsc = (float*)(wch + Ss * 4 * 2 * 64 * 8);
    float* bnsh = bnsc + Cc;

    gcn_pre<<<dim3(1), 256, 0, stream>>>(A, PA1, PA2, Wc, bc, gamma, beta, rmean, rvar,
                                         aeh, wch, bnsc, bnsh);
    // (15, 64) = 960 blocks -> ~1.9 rounds at 2 blocks/CU
    gcn_main<<<dim3(Tt / (4 * KCH), Nn), 256, 0, stream>>>(x, aeh, wch, bnsc, bnsh, out);
}